// Round 14
// baseline (459.830 us; speedup 1.0000x reference)
//
#include <hip/hip_runtime.h>
#include <hip/hip_bf16.h>

typedef unsigned int u32;
typedef unsigned short u16;

#define NN 50000
#define EE 800000
#define TT 3

// ws layout (dword offsets) — total 8,153,024 dwords = 32.6 MiB
#define OFF_C1     0         // 1536 f
#define OFF_C2     1536      // 192 f
#define OFF_CNT    1728      // 50000 i (memset-zeroed)
#define OFF_FLAG   51728     // 2 i (memset-zeroed, unused)
#define OFF_OPART  51732     // 1024 f (memset-zeroed)
#define OFF_ROWPTR 52756     // 50004 i
#define OFF_CNT2   102760    // 50000 i
#define OFF_BSUM   152760    // 256 i
#define OFF_PSRC   153016    // 800000 i (src | etype<<20, dst-sorted)
#define OFF_PK1    953024    // N*3 rows * 32 dw: [16 dw fp8 F][4 dw bf16 EP][12 pad] (128B-aligned rows)
#define OFF_PK2    5753024   // N*3 rows * 16 dw: [8 dw bf16 F2][1 dw EG f32][7 pad] (64B-aligned rows)
// memset range: dword 1728 .. 52755 (CNT+FLAG+OPART) = 51028 dwords

__device__ __forceinline__ float bf2f(u32 u) {
    union { u32 i; float f; } v; v.i = u << 16; return v.f;
}
__device__ __forceinline__ u32 f2bf(float f) {  // RNE
    union { float f; u32 i; } v; v.f = f;
    return (v.i + 0x7fffu + ((v.i >> 16) & 1u)) >> 16;
}

// C1[t][k][h] = sum_k2 W1[t][k][k2] * sum_j (al1+ar1)[t][k2][h*8+j]
// c2[t][k]   = sum_k2 W2[t][k][k2] * sum_j (al2+ar2)[t][k2][j]
__global__ void precompute(const float* __restrict__ W1, const float* __restrict__ al1,
                           const float* __restrict__ ar1, const float* __restrict__ W2,
                           const float* __restrict__ al2, const float* __restrict__ ar2,
                           float* __restrict__ ws) {
    __shared__ float a1c[64][8];
    __shared__ float a2c[16];
    int t = blockIdx.x;
    int tid = threadIdx.x;
    {
        int k2 = tid >> 3, hh = tid & 7;
        float s = 0.f;
#pragma unroll
        for (int j = 0; j < 8; ++j) {
            int idx = t * 4096 + k2 * 64 + hh * 8 + j;
            s += al1[idx] + ar1[idx];
        }
        a1c[k2][hh] = s;
    }
    if (tid < 16) {
        float s = 0.f;
#pragma unroll
        for (int j = 0; j < 16; ++j) {
            int idx = t * 256 + tid * 16 + j;
            s += al2[idx] + ar2[idx];
        }
        a2c[tid] = s;
    }
    __syncthreads();
    {
        int k = tid >> 3, hh = tid & 7;
        float s = 0.f;
#pragma unroll
        for (int k2 = 0; k2 < 64; ++k2)
            s += W1[t * 4096 + k * 64 + k2] * a1c[k2][hh];
        ws[OFF_C1 + t * 512 + k * 8 + hh] = s;
    }
    if (tid < 64) {
        float s = 0.f;
#pragma unroll
        for (int k2 = 0; k2 < 16; ++k2)
            s += W2[t * 1024 + tid * 16 + k2] * a2c[k2];
        ws[OFF_C2 + t * 64 + tid] = s;
    }
}

__global__ __launch_bounds__(256) void hist_k(const int* __restrict__ dst, int* wsi) {
    int e = blockIdx.x * 256 + threadIdx.x;
    if (e < EE) atomicAdd(wsi + OFF_CNT + dst[e], 1);
}

__global__ __launch_bounds__(256) void scan1(int* wsi) {
    __shared__ int sd[256];
    int t = threadIdx.x;
    int i = blockIdx.x * 256 + t;
    int v = (i < NN) ? wsi[OFF_CNT + i] : 0;
    sd[t] = v;
    __syncthreads();
    for (int o = 128; o > 0; o >>= 1) {
        if (t < o) sd[t] += sd[t + o];
        __syncthreads();
    }
    if (t == 0) wsi[OFF_BSUM + blockIdx.x] = sd[0];
}

__global__ __launch_bounds__(256) void scan2(int* wsi) {
    __shared__ int sd[256];
    int t = threadIdx.x;
    int v = (t < 196) ? wsi[OFF_BSUM + t] : 0;
    sd[t] = v;
    __syncthreads();
    for (int o = 1; o < 256; o <<= 1) {
        int u = (t >= o) ? sd[t - o] : 0;
        __syncthreads();
        sd[t] += u;
        __syncthreads();
    }
    wsi[OFF_BSUM + t] = sd[t] - v;  // exclusive
    if (t == 0) wsi[OFF_ROWPTR + NN] = EE;
}

__global__ __launch_bounds__(256) void scan3(int* wsi) {
    __shared__ int sd[256];
    int t = threadIdx.x;
    int i = blockIdx.x * 256 + t;
    int v = (i < NN) ? wsi[OFF_CNT + i] : 0;
    sd[t] = v;
    __syncthreads();
    for (int o = 1; o < 256; o <<= 1) {
        int u = (t >= o) ? sd[t - o] : 0;
        __syncthreads();
        sd[t] += u;
        __syncthreads();
    }
    if (i < NN) {
        int ex = wsi[OFF_BSUM + blockIdx.x] + sd[t] - v;
        wsi[OFF_ROWPTR + i] = ex;
        wsi[OFF_CNT2 + i] = ex;
    }
}

__global__ __launch_bounds__(256) void scatter_k(const int* __restrict__ src, const int* __restrict__ dst,
                          const int* __restrict__ etype, int* wsi) {
    int e = blockIdx.x * 256 + threadIdx.x;
    if (e >= EE) return;
    int d = dst[e];
    int slot = atomicAdd(wsi + OFF_CNT2 + d, 1);
    wsi[OFF_PSRC + slot] = src[e] | (etype[e] << 20);
}

// PK1[n][t] row (32 dw): F fp8 (dw 0-15) + EP bf16 (dw 16-19).
// F[n][t][c] = x[n].W1[t][:,c]; EP[n][t][h] = exp(leaky(x[n].C1[t][:,h])).
__global__ __launch_bounds__(256) void gemm_f(const float* __restrict__ x, const float* __restrict__ W1,
                       float* __restrict__ ws) {
    __shared__ alignas(16) float CW[64 * 224];
    __shared__ alignas(16) float Xs[64 * 65];
    int tid = threadIdx.x;
    int n0 = blockIdx.x * 64;
    for (int q = tid; q < 14336; q += 256) {
        int k = q / 224, c = q - k * 224;
        float v;
        if (c < 192) v = W1[(c >> 6) * 4096 + k * 64 + (c & 63)];
        else if (c < 216) v = ws[OFF_C1 + ((c - 192) >> 3) * 512 + k * 8 + ((c - 192) & 7)];
        else v = 0.f;
        CW[k * 224 + c] = v;
    }
    {
        const float4* xg = (const float4*)(x + (size_t)n0 * 64);
        for (int q = tid; q < 1024; q += 256) {
            int row = q >> 4;
            float4 v = (n0 + row < NN) ? xg[q] : make_float4(0.f, 0.f, 0.f, 0.f);
            *(float4*)(Xs + row * 65 + (q & 15) * 4) = v;
        }
    }
    __syncthreads();
    int ng = tid >> 3, cg = tid & 7;
    int cbase = cg * 28;
    float acc0[28], acc1[28];
#pragma unroll
    for (int i = 0; i < 28; ++i) { acc0[i] = 0.f; acc1[i] = 0.f; }
    const float* x0 = Xs + (2 * ng) * 65;
    const float* x1 = x0 + 65;
    for (int k = 0; k < 64; ++k) {
        float a = x0[k], b = x1[k];
        const float4* cw4 = (const float4*)(CW + k * 224 + cbase);
#pragma unroll
        for (int i = 0; i < 7; ++i) {
            float4 w4 = cw4[i];
            acc0[4*i+0] += a * w4.x; acc0[4*i+1] += a * w4.y;
            acc0[4*i+2] += a * w4.z; acc0[4*i+3] += a * w4.w;
            acc1[4*i+0] += b * w4.x; acc1[4*i+1] += b * w4.y;
            acc1[4*i+2] += b * w4.z; acc1[4*i+3] += b * w4.w;
        }
    }
#pragma unroll
    for (int j = 0; j < 2; ++j) {
        int n = n0 + 2 * ng + j;
        if (n < NN) {
            const float* accf = j ? acc1 : acc0;
            u32* row = (u32*)ws + OFF_PK1 + (size_t)n * 96;  // n*3 rows * 32 dw
#pragma unroll
            for (int g = 0; g < 7; ++g) {
                int col = cbase + 4 * g;
                float v0 = accf[4*g], v1 = accf[4*g+1], v2 = accf[4*g+2], v3 = accf[4*g+3];
                if (col < 192) {
                    int t = col >> 6, ci = col & 63;
                    int dw = __builtin_amdgcn_cvt_pk_fp8_f32(v0, v1, 0, false);
                    dw = __builtin_amdgcn_cvt_pk_fp8_f32(v2, v3, dw, true);
                    row[t * 32 + (ci >> 2)] = (u32)dw;
                } else if (col < 216) {
                    int jj = col - 192;
                    int t = jj >> 3, rem = jj & 7;  // rem in {0,4}
                    v0 = v0 > 0.f ? v0 : 0.2f * v0;
                    v1 = v1 > 0.f ? v1 : 0.2f * v1;
                    v2 = v2 > 0.f ? v2 : 0.2f * v2;
                    v3 = v3 > 0.f ? v3 : 0.2f * v3;
                    row[t * 32 + 16 + (rem >> 1)]     = f2bf(__expf(v0)) | (f2bf(__expf(v1)) << 16);
                    row[t * 32 + 16 + (rem >> 1) + 1] = f2bf(__expf(v2)) | (f2bf(__expf(v3)) << 16);
                }
            }
        }
    }
}

// layer0 fused softmax+aggregate + layer-2 prep. One wave per dst (r12-proven loop,
// PK1 single-line gathers). Tail: F2/EG (PK2) + residual partials, CW staged in LDS.
__global__ __launch_bounds__(256) void agg1(const int* __restrict__ wsi, float* __restrict__ ws,
                     const float* __restrict__ W2, const float* __restrict__ res_w) {
    __shared__ float CWs[64 * 68];  // [k][0..47 W2(t*16+c2) | 48..50 c2 | 51..66 res_w | 67 pad]
    __shared__ float hrow[4][64];
    __shared__ float routs[4][16];
    int tid = threadIdx.x;
    for (int q = tid; q < 4352; q += 256) {
        int k = q / 68, cc = q - k * 68;
        float v;
        if (cc < 48) v = W2[(cc >> 4) * 1024 + k * 16 + (cc & 15)];
        else if (cc < 51) v = ws[OFF_C2 + (cc - 48) * 64 + k];
        else if (cc < 67) v = res_w[k * 16 + (cc - 51)];
        else v = 0.f;
        CWs[q] = v;
    }
    __syncthreads();
    int wave = tid >> 6;
    int lane = tid & 63;
    int d = blockIdx.x * 4 + wave;
    int c = lane;
    int h4 = c >> 3;
    int dwF = c >> 2, shF = (c & 3) * 8;
    int sh_ep = (h4 & 1) * 16;
    int epw = h4 >> 1;
    int start = wsi[OFF_ROWPTR + d], end = wsi[OFF_ROWPTR + d + 1];
    const u32* pk = (const u32*)ws + OFF_PK1;
    const int* psrc = wsi + OFF_PSRC;
    float acc = 0.f, den = 0.f;
    u32 fdw_c = 0, epdw_c = 0;
    if (start < end) {
        int p = psrc[start];
        int sn = p & 0xFFFFF, t = p >> 20;
        size_t base = (size_t)(sn * 3 + t) * 32;
        fdw_c = pk[base + dwF];
        epdw_c = pk[base + 16 + epw];
    }
    for (int s = start; s < end; ++s) {
        u32 fdw = fdw_c, epdw = epdw_c;
        if (s + 1 < end) {
            int p = psrc[s + 1];
            int sn = p & 0xFFFFF, t = p >> 20;
            size_t base = (size_t)(sn * 3 + t) * 32;
            fdw_c = pk[base + dwF];
            epdw_c = pk[base + 16 + epw];
        }
        float w = bf2f((epdw >> sh_ep) & 0xffffu);
        float m = __builtin_amdgcn_cvt_f32_fp8((int)(fdw >> shF), 0);
        den += w;
        acc += w * m;
    }
    float dn = (end > start) ? den : 1.f;
    float v = acc / dn;
    v = v > 0.f ? v : __expf(v) - 1.f;  // ELU -> H[d][c]
    hrow[wave][lane] = v;
    // --- fused layer-2 prep (reads own wave's hrow; CW staged) ---
    int t2 = lane >> 4, c2 = lane & 15;
    int off = (lane < 48) ? (t2 * 16 + c2) : (51 + c2);
    const float* hv = hrow[wave];
    const float* cb = CWs + off;
    float dot = 0.f;
#pragma unroll 8
    for (int k = 0; k < 64; ++k) dot += hv[k] * cb[k * 68];
    u16* pk2u = (u16*)((u32*)ws + OFF_PK2);
    if (lane < 48) {
        pk2u[((size_t)d * 3 + t2) * 32 + c2] = (u16)f2bf(dot);  // F2 bf16
    } else {
        routs[wave][c2] = dot;  // residual partial
    }
    if (lane < 3) {  // EG
        const float* cg = CWs + 48 + lane;
        float pr = 0.f;
#pragma unroll 8
        for (int k = 0; k < 64; ++k) pr += hv[k] * cg[k * 68];
        pr = pr > 0.f ? pr : 0.2f * pr;
        ((float*)ws)[OFF_PK2 + ((size_t)d * 3 + lane) * 16 + 8] = __expf(pr);
    }
    __syncthreads();
    if (tid < 16) {
        float s = routs[0][tid] + routs[1][tid] + routs[2][tid] + routs[3][tid];
        atomicAdd(ws + OFF_OPART + (blockIdx.x & 63) * 16 + tid, s);
    }
}

// layer1 fused — r7-proven body, PK2 single-line gathers.
__global__ __launch_bounds__(256) void agg2(const int* __restrict__ wsi, float* __restrict__ ws) {
    __shared__ float outs[4][16];
    int tid = threadIdx.x;
    int wave = tid >> 6, lane = tid & 63;
    int q = lane >> 4, c = lane & 15;
    int d = blockIdx.x * 4 + wave;
    int start = wsi[OFF_ROWPTR + d], end = wsi[OFF_ROWPTR + d + 1];
    const u16* pk2u = (const u16*)((const u32*)ws + OFF_PK2);
    const float* pk2f = ws + OFF_PK2;
    const int* psrc = wsi + OFF_PSRC;
    float acc = 0.f, den = 0.f;
    int s = start + q;
    float w_c = 0.f, m_c = 0.f;
    bool valid = s < end;
    if (valid) {
        int p = psrc[s];
        int sn = p & 0xFFFFF, t = p >> 20;
        size_t r = (size_t)(sn * 3 + t);
        w_c = pk2f[r * 16 + 8];
        m_c = bf2f(pk2u[r * 32 + c]);
    }
    while (valid) {
        float w = w_c, m = m_c;
        int s2 = s + 4;
        bool v2 = s2 < end;
        if (v2) {
            int p = psrc[s2];
            int sn = p & 0xFFFFF, t = p >> 20;
            size_t r = (size_t)(sn * 3 + t);
            w_c = pk2f[r * 16 + 8];
            m_c = bf2f(pk2u[r * 32 + c]);
        }
        den += w;
        acc += w * m;
        s = s2; valid = v2;
    }
    acc += __shfl_xor(acc, 16);
    acc += __shfl_xor(acc, 32);
    den += __shfl_xor(den, 16);
    den += __shfl_xor(den, 32);
    float val = (end > start) ? acc / den : 0.f;
    if (q == 0) outs[wave][c] = val;
    __syncthreads();
    if (tid < 16) {
        float sum = outs[0][tid] + outs[1][tid] + outs[2][tid] + outs[3][tid];
        atomicAdd(ws + OFF_OPART + (blockIdx.x & 63) * 16 + tid, sum);
    }
}

__global__ void final_k(const float* __restrict__ res_b, float* __restrict__ ws, float* __restrict__ out) {
    int c = threadIdx.x;
    if (c < 16) {
        float s = 0.f;
        for (int r = 0; r < 64; ++r) s += ws[OFF_OPART + r * 16 + c];
        out[c] = s * (1.0f / (float)NN) + res_b[c];
    }
}

extern "C" void kernel_launch(void* const* d_in, const int* in_sizes, int n_in,
                              void* d_out, int out_size, void* d_ws, size_t ws_size,
                              hipStream_t stream) {
    const float* x     = (const float*)d_in[0];
    const int*   src   = (const int*)d_in[1];
    const int*   dst   = (const int*)d_in[2];
    // d_in[3] = ntype (unused by reference)
    const int*   etype = (const int*)d_in[4];
    const float* W1    = (const float*)d_in[5];
    const float* al1   = (const float*)d_in[6];
    const float* ar1   = (const float*)d_in[7];
    const float* W2    = (const float*)d_in[8];
    const float* al2   = (const float*)d_in[9];
    const float* ar2   = (const float*)d_in[10];
    const float* res_w = (const float*)d_in[11];
    const float* res_b = (const float*)d_in[12];
    float* ws = (float*)d_ws;
    int* wsi = (int*)d_ws;
    float* out = (float*)d_out;

    hipMemsetAsync((char*)d_ws + (size_t)OFF_CNT * 4, 0, (size_t)51028 * 4, stream);
    hipLaunchKernelGGL(precompute, dim3(TT), dim3(512), 0, stream, W1, al1, ar1, W2, al2, ar2, ws);
    hipLaunchKernelGGL(hist_k, dim3((EE + 255) / 256), dim3(256), 0, stream, dst, wsi);
    hipLaunchKernelGGL(scan1, dim3(196), dim3(256), 0, stream, wsi);
    hipLaunchKernelGGL(scan2, dim3(1), dim3(256), 0, stream, wsi);
    hipLaunchKernelGGL(scan3, dim3(196), dim3(256), 0, stream, wsi);
    hipLaunchKernelGGL(scatter_k, dim3((EE + 255) / 256), dim3(256), 0, stream, src, dst, etype, wsi);
    hipLaunchKernelGGL(gemm_f, dim3((NN + 63) / 64), dim3(256), 0, stream, x, W1, ws);
    hipLaunchKernelGGL(agg1, dim3(NN / 4), dim3(256), 0, stream, wsi, ws, W2, res_w);
    hipLaunchKernelGGL(agg2, dim3(NN / 4), dim3(256), 0, stream, wsi, ws);
    hipLaunchKernelGGL(final_k, dim3(1), dim3(64), 0, stream, res_b, ws, out);
}

// Round 15
// 399.274 us; speedup vs baseline: 1.1517x; 1.1517x over previous
//
#include <hip/hip_runtime.h>
#include <hip/hip_bf16.h>

typedef unsigned int u32;
typedef unsigned short u16;

#define NN 50000
#define EE 800000
#define TT 3

// ws layout (dword offsets) — total 8,953,024 dwords = 35.8 MiB
#define OFF_C1     0         // 1536 f
#define OFF_C2     1536      // 192 f
#define OFF_CNT    1728      // 50000 i (memset-zeroed)
#define OFF_FLAG   51728     // 2 i (memset-zeroed, unused)
#define OFF_OPART  51732     // 1024 f (memset-zeroed)
#define OFF_ROWPTR 52756     // 50004 i
#define OFF_CNT2   102760    // 50000 i
#define OFF_BSUM   152760    // 256 i
#define OFF_PSRC   153016    // 800000 i (src | etype<<20, dst-sorted)
#define OFF_PK1    953024    // N*3 rows * 32 dw: [16 dw fp8 F][4 dw bf16 EP][12 pad]
#define OFF_PK2    953024    // overlays PK1 (dead after agg1): N*3 rows * 16 dw: [8 dw bf16 F2][EG f32][7 pad]
#define OFF_H      5753024   // N*64 f = 3,200,000
// memset range: dword 1728 .. 52755 (CNT+FLAG+OPART) = 51028 dwords

__device__ __forceinline__ float bf2f(u32 u) {
    union { u32 i; float f; } v; v.i = u << 16; return v.f;
}
__device__ __forceinline__ u32 f2bf(float f) {  // RNE
    union { float f; u32 i; } v; v.f = f;
    return (v.i + 0x7fffu + ((v.i >> 16) & 1u)) >> 16;
}

// C1[t][k][h] = sum_k2 W1[t][k][k2] * sum_j (al1+ar1)[t][k2][h*8+j]
// c2[t][k]   = sum_k2 W2[t][k][k2] * sum_j (al2+ar2)[t][k2][j]
__global__ void precompute(const float* __restrict__ W1, const float* __restrict__ al1,
                           const float* __restrict__ ar1, const float* __restrict__ W2,
                           const float* __restrict__ al2, const float* __restrict__ ar2,
                           float* __restrict__ ws) {
    __shared__ float a1c[64][8];
    __shared__ float a2c[16];
    int t = blockIdx.x;
    int tid = threadIdx.x;
    {
        int k2 = tid >> 3, hh = tid & 7;
        float s = 0.f;
#pragma unroll
        for (int j = 0; j < 8; ++j) {
            int idx = t * 4096 + k2 * 64 + hh * 8 + j;
            s += al1[idx] + ar1[idx];
        }
        a1c[k2][hh] = s;
    }
    if (tid < 16) {
        float s = 0.f;
#pragma unroll
        for (int j = 0; j < 16; ++j) {
            int idx = t * 256 + tid * 16 + j;
            s += al2[idx] + ar2[idx];
        }
        a2c[tid] = s;
    }
    __syncthreads();
    {
        int k = tid >> 3, hh = tid & 7;
        float s = 0.f;
#pragma unroll
        for (int k2 = 0; k2 < 64; ++k2)
            s += W1[t * 4096 + k * 64 + k2] * a1c[k2][hh];
        ws[OFF_C1 + t * 512 + k * 8 + hh] = s;
    }
    if (tid < 64) {
        float s = 0.f;
#pragma unroll
        for (int k2 = 0; k2 < 16; ++k2)
            s += W2[t * 1024 + tid * 16 + k2] * a2c[k2];
        ws[OFF_C2 + t * 64 + tid] = s;
    }
}

__global__ __launch_bounds__(256) void hist_k(const int* __restrict__ dst, int* wsi) {
    int e = blockIdx.x * 256 + threadIdx.x;
    if (e < EE) atomicAdd(wsi + OFF_CNT + dst[e], 1);
}

__global__ __launch_bounds__(256) void scan1(int* wsi) {
    __shared__ int sd[256];
    int t = threadIdx.x;
    int i = blockIdx.x * 256 + t;
    int v = (i < NN) ? wsi[OFF_CNT + i] : 0;
    sd[t] = v;
    __syncthreads();
    for (int o = 128; o > 0; o >>= 1) {
        if (t < o) sd[t] += sd[t + o];
        __syncthreads();
    }
    if (t == 0) wsi[OFF_BSUM + blockIdx.x] = sd[0];
}

__global__ __launch_bounds__(256) void scan2(int* wsi) {
    __shared__ int sd[256];
    int t = threadIdx.x;
    int v = (t < 196) ? wsi[OFF_BSUM + t] : 0;
    sd[t] = v;
    __syncthreads();
    for (int o = 1; o < 256; o <<= 1) {
        int u = (t >= o) ? sd[t - o] : 0;
        __syncthreads();
        sd[t] += u;
        __syncthreads();
    }
    wsi[OFF_BSUM + t] = sd[t] - v;  // exclusive
    if (t == 0) wsi[OFF_ROWPTR + NN] = EE;
}

__global__ __launch_bounds__(256) void scan3(int* wsi) {
    __shared__ int sd[256];
    int t = threadIdx.x;
    int i = blockIdx.x * 256 + t;
    int v = (i < NN) ? wsi[OFF_CNT + i] : 0;
    sd[t] = v;
    __syncthreads();
    for (int o = 1; o < 256; o <<= 1) {
        int u = (t >= o) ? sd[t - o] : 0;
        __syncthreads();
        sd[t] += u;
        __syncthreads();
    }
    if (i < NN) {
        int ex = wsi[OFF_BSUM + blockIdx.x] + sd[t] - v;
        wsi[OFF_ROWPTR + i] = ex;
        wsi[OFF_CNT2 + i] = ex;
    }
}

__global__ __launch_bounds__(256) void scatter_k(const int* __restrict__ src, const int* __restrict__ dst,
                          const int* __restrict__ etype, int* wsi) {
    int e = blockIdx.x * 256 + threadIdx.x;
    if (e >= EE) return;
    int d = dst[e];
    int slot = atomicAdd(wsi + OFF_CNT2 + d, 1);
    wsi[OFF_PSRC + slot] = src[e] | (etype[e] << 20);
}

// PK1[n][t] row (32 dw): F fp8 (dw 0-15) + EP bf16 (dw 16-19).
__global__ __launch_bounds__(256) void gemm_f(const float* __restrict__ x, const float* __restrict__ W1,
                       float* __restrict__ ws) {
    __shared__ alignas(16) float CW[64 * 224];
    __shared__ alignas(16) float Xs[64 * 65];
    int tid = threadIdx.x;
    int n0 = blockIdx.x * 64;
    for (int q = tid; q < 14336; q += 256) {
        int k = q / 224, c = q - k * 224;
        float v;
        if (c < 192) v = W1[(c >> 6) * 4096 + k * 64 + (c & 63)];
        else if (c < 216) v = ws[OFF_C1 + ((c - 192) >> 3) * 512 + k * 8 + ((c - 192) & 7)];
        else v = 0.f;
        CW[k * 224 + c] = v;
    }
    {
        const float4* xg = (const float4*)(x + (size_t)n0 * 64);
        for (int q = tid; q < 1024; q += 256) {
            int row = q >> 4;
            float4 v = (n0 + row < NN) ? xg[q] : make_float4(0.f, 0.f, 0.f, 0.f);
            *(float4*)(Xs + row * 65 + (q & 15) * 4) = v;
        }
    }
    __syncthreads();
    int ng = tid >> 3, cg = tid & 7;
    int cbase = cg * 28;
    float acc0[28], acc1[28];
#pragma unroll
    for (int i = 0; i < 28; ++i) { acc0[i] = 0.f; acc1[i] = 0.f; }
    const float* x0 = Xs + (2 * ng) * 65;
    const float* x1 = x0 + 65;
    for (int k = 0; k < 64; ++k) {
        float a = x0[k], b = x1[k];
        const float4* cw4 = (const float4*)(CW + k * 224 + cbase);
#pragma unroll
        for (int i = 0; i < 7; ++i) {
            float4 w4 = cw4[i];
            acc0[4*i+0] += a * w4.x; acc0[4*i+1] += a * w4.y;
            acc0[4*i+2] += a * w4.z; acc0[4*i+3] += a * w4.w;
            acc1[4*i+0] += b * w4.x; acc1[4*i+1] += b * w4.y;
            acc1[4*i+2] += b * w4.z; acc1[4*i+3] += b * w4.w;
        }
    }
#pragma unroll
    for (int j = 0; j < 2; ++j) {
        int n = n0 + 2 * ng + j;
        if (n < NN) {
            const float* accf = j ? acc1 : acc0;
            u32* row = (u32*)ws + OFF_PK1 + (size_t)n * 96;
#pragma unroll
            for (int g = 0; g < 7; ++g) {
                int col = cbase + 4 * g;
                float v0 = accf[4*g], v1 = accf[4*g+1], v2 = accf[4*g+2], v3 = accf[4*g+3];
                if (col < 192) {
                    int t = col >> 6, ci = col & 63;
                    int dw = __builtin_amdgcn_cvt_pk_fp8_f32(v0, v1, 0, false);
                    dw = __builtin_amdgcn_cvt_pk_fp8_f32(v2, v3, dw, true);
                    row[t * 32 + (ci >> 2)] = (u32)dw;
                } else if (col < 216) {
                    int jj = col - 192;
                    int t = jj >> 3, rem = jj & 7;  // rem in {0,4}
                    v0 = v0 > 0.f ? v0 : 0.2f * v0;
                    v1 = v1 > 0.f ? v1 : 0.2f * v1;
                    v2 = v2 > 0.f ? v2 : 0.2f * v2;
                    v3 = v3 > 0.f ? v3 : 0.2f * v3;
                    row[t * 32 + 16 + (rem >> 1)]     = f2bf(__expf(v0)) | (f2bf(__expf(v1)) << 16);
                    row[t * 32 + 16 + (rem >> 1) + 1] = f2bf(__expf(v2)) | (f2bf(__expf(v3)) << 16);
                }
            }
        }
    }
}

// layer0 fused softmax+aggregate — r12-proven body, PK1 single-line gathers, plain H write.
__global__ __launch_bounds__(256) void agg1(const int* __restrict__ wsi, float* __restrict__ ws) {
    int tid = threadIdx.x;
    int d = blockIdx.x * 4 + (tid >> 6);
    int c = tid & 63;
    int h4 = c >> 3;
    int dwF = c >> 2, shF = (c & 3) * 8;
    int sh_ep = (h4 & 1) * 16;
    int epw = h4 >> 1;
    int start = wsi[OFF_ROWPTR + d], end = wsi[OFF_ROWPTR + d + 1];
    const u32* pk = (const u32*)ws + OFF_PK1;
    const int* psrc = wsi + OFF_PSRC;
    float acc = 0.f, den = 0.f;
    u32 fdw_c = 0, epdw_c = 0;
    if (start < end) {
        int p = psrc[start];
        int sn = p & 0xFFFFF, t = p >> 20;
        size_t base = (size_t)(sn * 3 + t) * 32;
        fdw_c = pk[base + dwF];
        epdw_c = pk[base + 16 + epw];
    }
    for (int s = start; s < end; ++s) {
        u32 fdw = fdw_c, epdw = epdw_c;
        if (s + 1 < end) {
            int p = psrc[s + 1];
            int sn = p & 0xFFFFF, t = p >> 20;
            size_t base = (size_t)(sn * 3 + t) * 32;
            fdw_c = pk[base + dwF];
            epdw_c = pk[base + 16 + epw];
        }
        float w = bf2f((epdw >> sh_ep) & 0xffffu);
        float m = __builtin_amdgcn_cvt_f32_fp8((int)(fdw >> shF), 0);
        den += w;
        acc += w * m;
    }
    float dn = (end > start) ? den : 1.f;
    float v = acc / dn;
    v = v > 0.f ? v : __expf(v) - 1.f;  // ELU
    ws[OFF_H + (size_t)d * 64 + c] = v;
}

// PK2[n][t] = [16 bf16 F2][EG f32]; residual partials to OPART. (r12-proven structure)
__global__ __launch_bounds__(256) void gemm_f2(const float* __restrict__ W2, const float* __restrict__ res_w,
                        float* __restrict__ ws) {
    __shared__ alignas(16) float CW[64 * 68];
    __shared__ alignas(16) float Hs[64 * 65];
    __shared__ float Rs[64][17];
    int tid = threadIdx.x;
    int n0 = blockIdx.x * 64;
    for (int q = tid; q < 4352; q += 256) {
        int k = q / 68, c = q - k * 68;
        float v;
        if (c < 48) v = W2[(c >> 4) * 1024 + k * 16 + (c & 15)];
        else if (c < 51) v = ws[OFF_C2 + (c - 48) * 64 + k];
        else if (c < 67) v = res_w[k * 16 + (c - 51)];
        else v = 0.f;
        CW[k * 68 + c] = v;
    }
    {
        const float4* hg = (const float4*)(ws + OFF_H + (size_t)n0 * 64);
        for (int q = tid; q < 1024; q += 256) {
            int row = q >> 4;
            float4 v = (n0 + row < NN) ? hg[q] : make_float4(0.f, 0.f, 0.f, 0.f);
            *(float4*)(Hs + row * 65 + (q & 15) * 4) = v;
        }
    }
    __syncthreads();
    int node = tid >> 2, cb = tid & 3;
    int cbase = cb * 17;
    float acc[17];
#pragma unroll
    for (int i = 0; i < 17; ++i) acc[i] = 0.f;
    const float* hrow = Hs + node * 65;
    for (int k = 0; k < 64; ++k) {
        float hv = hrow[k];
        const float* cwk = CW + k * 68 + cbase;
#pragma unroll
        for (int i = 0; i < 17; ++i) acc[i] += hv * cwk[i];
    }
    int n = n0 + node;
    u16* pk2u = (u16*)((u32*)ws + OFF_PK2);
#pragma unroll
    for (int i = 0; i < 17; ++i) {
        int col = cbase + i;
        if (col < 48) {
            if (n < NN) {
                int t = col >> 4, c2 = col & 15;
                pk2u[((size_t)n * 3 + t) * 32 + c2] = (u16)f2bf(acc[i]);
            }
        } else if (col < 51) {
            if (n < NN) {
                float v = acc[i]; v = v > 0.f ? v : 0.2f * v;
                ws[OFF_PK2 + ((size_t)n * 3 + (col - 48)) * 16 + 8] = __expf(v);
            }
        } else if (col < 67) {
            Rs[node][col - 51] = acc[i];
        }
    }
    __syncthreads();
    if (tid < 16) {
        float s = 0.f;
#pragma unroll 8
        for (int r = 0; r < 64; ++r) s += Rs[r][tid];
        atomicAdd(ws + OFF_OPART + (blockIdx.x & 63) * 16 + tid, s);
    }
}

// layer1 fused — r7-proven body, PK2 single-line gathers.
__global__ __launch_bounds__(256) void agg2(const int* __restrict__ wsi, float* __restrict__ ws) {
    __shared__ float outs[4][16];
    int tid = threadIdx.x;
    int wave = tid >> 6, lane = tid & 63;
    int q = lane >> 4, c = lane & 15;
    int d = blockIdx.x * 4 + wave;
    int start = wsi[OFF_ROWPTR + d], end = wsi[OFF_ROWPTR + d + 1];
    const u16* pk2u = (const u16*)((const u32*)ws + OFF_PK2);
    const float* pk2f = ws + OFF_PK2;
    const int* psrc = wsi + OFF_PSRC;
    float acc = 0.f, den = 0.f;
    int s = start + q;
    float w_c = 0.f, m_c = 0.f;
    bool valid = s < end;
    if (valid) {
        int p = psrc[s];
        int sn = p & 0xFFFFF, t = p >> 20;
        size_t r = (size_t)(sn * 3 + t);
        w_c = pk2f[r * 16 + 8];
        m_c = bf2f(pk2u[r * 32 + c]);
    }
    while (valid) {
        float w = w_c, m = m_c;
        int s2 = s + 4;
        bool v2 = s2 < end;
        if (v2) {
            int p = psrc[s2];
            int sn = p & 0xFFFFF, t = p >> 20;
            size_t r = (size_t)(sn * 3 + t);
            w_c = pk2f[r * 16 + 8];
            m_c = bf2f(pk2u[r * 32 + c]);
        }
        den += w;
        acc += w * m;
        s = s2; valid = v2;
    }
    acc += __shfl_xor(acc, 16);
    acc += __shfl_xor(acc, 32);
    den += __shfl_xor(den, 16);
    den += __shfl_xor(den, 32);
    float val = (end > start) ? acc / den : 0.f;
    if (q == 0) outs[wave][c] = val;
    __syncthreads();
    if (tid < 16) {
        float sum = outs[0][tid] + outs[1][tid] + outs[2][tid] + outs[3][tid];
        atomicAdd(ws + OFF_OPART + (blockIdx.x & 63) * 16 + tid, sum);
    }
}

__global__ void final_k(const float* __restrict__ res_b, float* __restrict__ ws, float* __restrict__ out) {
    int c = threadIdx.x;
    if (c < 16) {
        float s = 0.f;
        for (int r = 0; r < 64; ++r) s += ws[OFF_OPART + r * 16 + c];
        out[c] = s * (1.0f / (float)NN) + res_b[c];
    }
}

extern "C" void kernel_launch(void* const* d_in, const int* in_sizes, int n_in,
                              void* d_out, int out_size, void* d_ws, size_t ws_size,
                              hipStream_t stream) {
    const float* x     = (const float*)d_in[0];
    const int*   src   = (const int*)d_in[1];
    const int*   dst   = (const int*)d_in[2];
    // d_in[3] = ntype (unused by reference)
    const int*   etype = (const int*)d_in[4];
    const float* W1    = (const float*)d_in[5];
    const float* al1   = (const float*)d_in[6];
    const float* ar1   = (const float*)d_in[7];
    const float* W2    = (const float*)d_in[8];
    const float* al2   = (const float*)d_in[9];
    const float* ar2   = (const float*)d_in[10];
    const float* res_w = (const float*)d_in[11];
    const float* res_b = (const float*)d_in[12];
    float* ws = (float*)d_ws;
    int* wsi = (int*)d_ws;
    float* out = (float*)d_out;

    hipMemsetAsync((char*)d_ws + (size_t)OFF_CNT * 4, 0, (size_t)51028 * 4, stream);
    hipLaunchKernelGGL(precompute, dim3(TT), dim3(512), 0, stream, W1, al1, ar1, W2, al2, ar2, ws);
    hipLaunchKernelGGL(hist_k, dim3((EE + 255) / 256), dim3(256), 0, stream, dst, wsi);
    hipLaunchKernelGGL(scan1, dim3(196), dim3(256), 0, stream, wsi);
    hipLaunchKernelGGL(scan2, dim3(1), dim3(256), 0, stream, wsi);
    hipLaunchKernelGGL(scan3, dim3(196), dim3(256), 0, stream, wsi);
    hipLaunchKernelGGL(scatter_k, dim3((EE + 255) / 256), dim3(256), 0, stream, src, dst, etype, wsi);
    hipLaunchKernelGGL(gemm_f, dim3((NN + 63) / 64), dim3(256), 0, stream, x, W1, ws);
    hipLaunchKernelGGL(agg1, dim3(NN / 4), dim3(256), 0, stream, wsi, ws);
    hipLaunchKernelGGL(gemm_f2, dim3((NN + 63) / 64), dim3(256), 0, stream, W2, res_w, ws);
    hipLaunchKernelGGL(agg2, dim3(NN / 4), dim3(256), 0, stream, wsi, ws);
    hipLaunchKernelGGL(final_k, dim3(1), dim3(64), 0, stream, res_b, ws, out);
}